// Round 13
// baseline (338.099 us; speedup 1.0000x reference)
//
#include <hip/hip_runtime.h>
#include <hip/hip_bf16.h>
#include <hip/hip_fp16.h>

#define DIM 64
#define RELS 32
#define SCAN_B 512
#define TILE_V 64

// ---- fp16 helpers ----
__device__ __forceinline__ unsigned int pk_h2(float a, float b) {
    __half2 h = __float22half2_rn(make_float2(a, b));
    return *reinterpret_cast<unsigned int*>(&h);
}
__device__ __forceinline__ float4 h4_to_f4(uint2 u) {
    __half2 h0 = *reinterpret_cast<__half2*>(&u.x);
    __half2 h1 = *reinterpret_cast<__half2*>(&u.y);
    float2 f0 = __half22float2(h0);
    float2 f1 = __half22float2(h1);
    return make_float4(f0.x, f0.y, f1.x, f1.y);
}

// ============ Kernel A: build_M + fp16 mirror, interleaved with 4-way-split degree ============
__global__ __launch_bounds__(256, 4) void buildM_deg(
    const float* __restrict__ ent, const float* __restrict__ rel,
    __hip_bfloat16* __restrict__ M, uint2* __restrict__ entH,
    const int* __restrict__ head, const int* __restrict__ uidx,
    unsigned int* __restrict__ degS,
    unsigned char* __restrict__ rank_e, unsigned char* __restrict__ rank_i,
    int nE, int E, int I, int gM, int Q, int NSEG) {
    __shared__ float4 entL[TILE_V * 17];
    __shared__ float relS[4][16][33];
    int tx = threadIdx.x;
    int bid = blockIdx.x;
    int g = bid / 7, slot = bid - g * 7;

    if (slot >= 2) {
        int t = (g * 5 + (slot - 2)) * 256 + tx;
        if (t < E + I) {
            int k = (t >= Q) + (t >= 2 * Q) + (t >= 3 * Q);
            unsigned int* dk = degS + (size_t)k * NSEG;
            if (t < E) {
                rank_e[t] = (unsigned char)atomicAdd(&dk[head[t]], 1u);
            } else {
                int e = t - E;
                rank_i[e] = (unsigned char)atomicAdd(&dk[nE + uidx[e]], 1u);
            }
        }
        return;
    }

    int mb = g * 2 + slot;
    if (mb >= gM) return;
    int vg = tx >> 4, rg = tx & 15;
    int base = mb * TILE_V;
    const float4* rel4 = (const float4*)rel;
    #pragma unroll
    for (int k = 0; k < 2; k++) {
        int idx = tx + k * 256;
        float4 v = rel4[idx];
        int r = idx >> 4, d4 = idx & 15;
        relS[0][d4][r] = v.x; relS[1][d4][r] = v.y;
        relS[2][d4][r] = v.z; relS[3][d4][r] = v.w;
    }
    const float4* ent4 = (const float4*)ent;
    #pragma unroll
    for (int k = 0; k < 4; k++) {
        int idx = tx + k * 256;
        int row = idx >> 4, col = idx & 15;
        int v = base + row;
        float4 val = make_float4(0.f, 0.f, 0.f, 0.f);
        if (v < nE) {
            val = ent4[(size_t)v * 16 + col];
            entH[(size_t)v * 16 + col] = make_uint2(pk_h2(val.x, val.y), pk_h2(val.z, val.w));
        }
        entL[row * 17 + col] = val;
    }
    __syncthreads();

    float acc[4][2] = {{0.f,0.f},{0.f,0.f},{0.f,0.f},{0.f,0.f}};
    int r0 = rg * 2;
    #pragma unroll 2
    for (int d4 = 0; d4 < 16; d4++) {
        float4 a0 = entL[(vg * 4 + 0) * 17 + d4];
        float4 a1 = entL[(vg * 4 + 1) * 17 + d4];
        float4 a2 = entL[(vg * 4 + 2) * 17 + d4];
        float4 a3 = entL[(vg * 4 + 3) * 17 + d4];
        float bx0 = relS[0][d4][r0],     by0 = relS[1][d4][r0];
        float bz0 = relS[2][d4][r0],     bw0 = relS[3][d4][r0];
        float bx1 = relS[0][d4][r0 + 1], by1 = relS[1][d4][r0 + 1];
        float bz1 = relS[2][d4][r0 + 1], bw1 = relS[3][d4][r0 + 1];
        acc[0][0] = fmaf(a0.x,bx0, fmaf(a0.y,by0, fmaf(a0.z,bz0, fmaf(a0.w,bw0, acc[0][0]))));
        acc[1][0] = fmaf(a1.x,bx0, fmaf(a1.y,by0, fmaf(a1.z,bz0, fmaf(a1.w,bw0, acc[1][0]))));
        acc[2][0] = fmaf(a2.x,bx0, fmaf(a2.y,by0, fmaf(a2.z,bz0, fmaf(a2.w,bw0, acc[2][0]))));
        acc[3][0] = fmaf(a3.x,bx0, fmaf(a3.y,by0, fmaf(a3.z,bz0, fmaf(a3.w,bw0, acc[3][0]))));
        acc[0][1] = fmaf(a0.x,bx1, fmaf(a0.y,by1, fmaf(a0.z,bz1, fmaf(a0.w,bw1, acc[0][1]))));
        acc[1][1] = fmaf(a1.x,bx1, fmaf(a1.y,by1, fmaf(a1.z,bz1, fmaf(a1.w,bw1, acc[1][1]))));
        acc[2][1] = fmaf(a2.x,bx1, fmaf(a2.y,by1, fmaf(a2.z,bz1, fmaf(a2.w,bw1, acc[2][1]))));
        acc[3][1] = fmaf(a3.x,bx1, fmaf(a3.y,by1, fmaf(a3.z,bz1, fmaf(a3.w,bw1, acc[3][1]))));
    }
    __hip_bfloat162* M2 = (__hip_bfloat162*)M;
    #pragma unroll
    for (int i = 0; i < 4; i++) {
        int v = base + vg * 4 + i;
        if (v < nE) {
            __hip_bfloat16 h0 = __float2bfloat16(acc[i][0] * 0.125f);
            __hip_bfloat16 h1 = __float2bfloat16(acc[i][1] * 0.125f);
            M2[(size_t)v * 16 + rg] = __halves2bfloat162(h0, h1);
        }
    }
}

// ---- Scan step 1 ----
__global__ __launch_bounds__(SCAN_B) void scan_partial(
    const unsigned int* __restrict__ degS, unsigned int* __restrict__ part, int n) {
    __shared__ unsigned int lds[SCAN_B];
    int i = blockIdx.x * SCAN_B + threadIdx.x;
    unsigned int v = 0;
    if (i < n) v = degS[i] + degS[n + i] + degS[2 * (size_t)n + i] + degS[3 * (size_t)n + i];
    lds[threadIdx.x] = v;
    __syncthreads();
    for (int off = SCAN_B >> 1; off > 0; off >>= 1) {
        if (threadIdx.x < off) lds[threadIdx.x] += lds[threadIdx.x + off];
        __syncthreads();
    }
    if (threadIdx.x == 0) part[blockIdx.x] = lds[0];
}

// ---- Scan step 2 ----
__global__ __launch_bounds__(1024) void scan_block(unsigned int* __restrict__ part, int nb) {
    __shared__ unsigned int lds[1024];
    int t = threadIdx.x;
    unsigned int v = (t < nb) ? part[t] : 0u;
    lds[t] = v;
    __syncthreads();
    for (int off = 1; off < 1024; off <<= 1) {
        unsigned int x = (t >= off) ? lds[t - off] : 0u;
        __syncthreads();
        lds[t] += x;
        __syncthreads();
    }
    if (t < nb) part[t] = lds[t] - v;
}

// ---- Scan step 3 ----
__global__ __launch_bounds__(SCAN_B) void scan_final(
    const unsigned int* __restrict__ degS, const unsigned int* __restrict__ part,
    unsigned int* __restrict__ offs0, unsigned int* __restrict__ offs123,
    int n, unsigned int total) {
    __shared__ unsigned int lds[SCAN_B];
    int t = threadIdx.x;
    int i = blockIdx.x * SCAN_B + t;
    unsigned int a0 = 0, a1 = 0, a2 = 0, a3 = 0, tot = 0;
    if (i < n) {
        a0 = degS[i]; a1 = degS[n + i];
        a2 = degS[2 * (size_t)n + i]; a3 = degS[3 * (size_t)n + i];
        tot = a0 + a1 + a2 + a3;
    }
    lds[t] = tot;
    __syncthreads();
    for (int off = 1; off < SCAN_B; off <<= 1) {
        unsigned int x = (t >= off) ? lds[t - off] : 0u;
        __syncthreads();
        lds[t] += x;
        __syncthreads();
    }
    if (i < n) {
        unsigned int base = part[blockIdx.x] + lds[t] - tot;
        offs0[i] = base;
        offs123[i] = base + a0;
        offs123[(size_t)n + i] = base + a0 + a1;
        offs123[2 * (size_t)n + i] = base + a0 + a1 + a2;
    }
    if (blockIdx.x == 0 && t == 0) offs0[n] = total;
}

// ---- Sort S1: 64-bucket degree histogram over a segment range ----
__global__ __launch_bounds__(256) void sort_hist(
    const unsigned int* __restrict__ offs0, unsigned int* __restrict__ bins,
    int lo, int n) {
    __shared__ unsigned int h[64];
    int tx = threadIdx.x;
    if (tx < 64) h[tx] = 0;
    __syncthreads();
    int i = blockIdx.x * 256 + tx;
    if (i < n) {
        int s = lo + i;
        unsigned int d = offs0[s + 1] - offs0[s];
        atomicAdd(&h[d < 63u ? d : 63u], 1u);
    }
    __syncthreads();
    if (tx < 64 && h[tx]) atomicAdd(&bins[tx], h[tx]);
}

// ---- Sort S2: two independent 64-bin exclusive scans -> cursors (order-array bases) ----
__global__ __launch_bounds__(128) void sort_scan(unsigned int* __restrict__ bins, int nE) {
    __shared__ unsigned int lds[128];
    int t = threadIdx.x;
    int half = t >> 6;
    unsigned int v = bins[t];
    lds[t] = v;
    __syncthreads();
    for (int off = 1; off < 64; off <<= 1) {
        unsigned int x = 0;
        if ((t & 63) >= off) x = lds[t - off];
        __syncthreads();
        lds[t] += x;
        __syncthreads();
    }
    bins[t] = (half ? (unsigned)nE : 0u) + lds[t] - v;   // exclusive prefix + range base
}

// ---- Sort S3: scatter segment ids into degree-sorted order ----
__global__ __launch_bounds__(256) void sort_scatter(
    const unsigned int* __restrict__ offs0, unsigned int* __restrict__ cursor,
    unsigned int* __restrict__ order, int lo, int n, int binBase) {
    __shared__ unsigned int lh[64], lbase[64];
    int tx = threadIdx.x;
    if (tx < 64) lh[tx] = 0;
    __syncthreads();
    int i = blockIdx.x * 256 + tx;
    unsigned int b = 0, r = 0;
    bool act = (i < n);
    int s = lo + i;
    if (act) {
        unsigned int d = offs0[s + 1] - offs0[s];
        b = d < 63u ? d : 63u;
        r = atomicAdd(&lh[b], 1u);
    }
    __syncthreads();
    if (tx < 64 && lh[tx]) lbase[tx] = atomicAdd(&cursor[binBase + tx], lh[tx]);
    __syncthreads();
    if (act) order[lbase[b] + r] = (unsigned int)s;
}

// ---- Scatter: single random-M pass; pay64={score,tail}; slotu for wout ----
__global__ __launch_bounds__(256) void scatter32(
    const __hip_bfloat16* __restrict__ M,
    const int* __restrict__ head, const int* __restrict__ tail, const int* __restrict__ etype,
    const int* __restrict__ uidx, const int* __restrict__ iidx, const int* __restrict__ ttype,
    const unsigned char* __restrict__ rank_e, const unsigned char* __restrict__ rank_i,
    const unsigned int* __restrict__ offs0, const unsigned int* __restrict__ offs123,
    unsigned long long* __restrict__ pay64, unsigned int* __restrict__ payu,
    float* __restrict__ e_sc, unsigned int* __restrict__ slotu,
    int E, int I, int nE, int Q, int NSEG) {
    int t = blockIdx.x * blockDim.x + threadIdx.x;
    if (t >= E + I) return;
    int k = (t >= Q) + (t >= 2 * Q) + (t >= 3 * Q);
    if (t < E) {
        int s = head[t];
        unsigned int base = (k == 0) ? offs0[s] : offs123[(size_t)(k - 1) * NSEG + s];
        int tl = tail[t];
        float sc = __bfloat162float(M[(size_t)tl * RELS + (etype[t] - 1)]);
        e_sc[t] = sc;
        unsigned int p = base + rank_e[t];
        unsigned long long v = ((unsigned long long)__float_as_uint(sc) << 32) | (unsigned int)tl;
        __builtin_nontemporal_store(v, &pay64[p]);
    } else {
        int e = t - E;
        int s = nE + uidx[e];
        unsigned int base = (k == 0) ? offs0[s] : offs123[(size_t)(k - 1) * NSEG + s];
        unsigned int p = base + rank_i[e] - (unsigned)E;
        unsigned int v = (unsigned int)iidx[e] | ((unsigned int)ttype[e] << 27);
        __builtin_nontemporal_store(v, &payu[p]);
        slotu[e] = p;
    }
}

// ============ Kernel C: degree-sorted segment order, single-stream online softmax ============
__global__ __launch_bounds__(256) void fused_agg(
    const uint2* __restrict__ entH, const float* __restrict__ usr,
    const float* __restrict__ itc,
    const unsigned long long* __restrict__ pay64, const unsigned int* __restrict__ payu,
    const unsigned int* __restrict__ offs0, const unsigned int* __restrict__ order,
    float* __restrict__ patt, float2* __restrict__ msum,
    float* __restrict__ aggE, float* __restrict__ aggU,
    int nE, int nU, int E, int gAE) {
    __shared__ float4 itcL[8][16];
    int tx = threadIdx.x;
    int bid = blockIdx.x;

    if (bid < gAE) {
        // ---- entity segments (degree-sorted order -> uniform d within wave) ----
        int t = bid * 256 + tx;
        int slot = t >> 4, l = t & 15;
        if (slot >= nE) return;
        int h = (int)order[slot];
        unsigned int off = offs0[h];
        unsigned int d = offs0[h + 1] - off;
        float m = -3.0e38f, s = 0.f, inv = 0.f;
        float4 acc = make_float4(0.f, 0.f, 0.f, 0.f);
        if (d) {
            unsigned long long v0 = pay64[off];
            uint2 b0 = entH[(size_t)(unsigned int)(v0 & 0xffffffffu) * 16 + l];
            for (unsigned int j = 0; j < d; j++) {
                unsigned long long v1 = v0; uint2 b1 = b0;
                if (j + 1 < d) {
                    v1 = pay64[off + j + 1];
                    b1 = entH[(size_t)(unsigned int)(v1 & 0xffffffffu) * 16 + l];
                }
                float sc = __uint_as_float((unsigned int)(v0 >> 32));
                float4 a0 = h4_to_f4(b0);
                float mn = fmaxf(m, sc);
                float scale = __expf(m - mn);
                float w = __expf(sc - mn);
                s = s * scale + w;
                acc.x = acc.x * scale + w * a0.x;
                acc.y = acc.y * scale + w * a0.y;
                acc.z = acc.z * scale + w * a0.z;
                acc.w = acc.w * scale + w * a0.w;
                m = mn; v0 = v1; b0 = b1;
            }
            inv = 1.f / s;
        }
        if (l == 0) msum[h] = make_float2(m, inv);
        acc.x *= inv; acc.y *= inv; acc.z *= inv; acc.w *= inv;
        ((float4*)(aggE + (size_t)h * DIM))[l] = acc;
        return;
    }

    // ---- user segments (degree-sorted order) ----
    if (tx < 128) itcL[tx >> 4][tx & 15] = ((const float4*)itc)[tx];
    __syncthreads();
    int t = (bid - gAE) * 256 + tx;
    int slot = t >> 4, l = t & 15;
    if (slot >= nU) return;
    int hs = (int)order[nE + slot];
    int h = hs - nE;
    unsigned int off = offs0[hs] - (unsigned)E;
    unsigned int d = offs0[hs + 1] - offs0[hs];
    float m = -3.0e38f, s = 0.f, inv = 0.f;
    float4 acc = make_float4(0.f, 0.f, 0.f, 0.f);
    float4 ur = ((const float4*)(usr + (size_t)h * DIM))[l];
    if (d) {
        unsigned int v0 = payu[off];
        uint2 b0 = entH[(size_t)(v0 & 0x7ffffffu) * 16 + l];
        for (unsigned int j = 0; j < d; j++) {
            unsigned int v1 = v0; uint2 b1 = b0;
            if (j + 1 < d) {
                v1 = payu[off + j + 1];
                b1 = entH[(size_t)(v1 & 0x7ffffffu) * 16 + l];
            }
            float4 a0 = h4_to_f4(b0);
            float4 c = itcL[v0 >> 27][l];
            float p = a0.x * ur.x * c.x + a0.y * ur.y * c.y
                    + a0.z * ur.z * c.z + a0.w * ur.w * c.w;
            p += __shfl_xor(p, 1);
            p += __shfl_xor(p, 2);
            p += __shfl_xor(p, 4);
            p += __shfl_xor(p, 8);
            if (l == 0) patt[off + j] = p;
            float mn = fmaxf(m, p);
            float scale = __expf(m - mn);
            float w = __expf(p - mn);
            s = s * scale + w;
            acc.x = acc.x * scale + w * a0.x;
            acc.y = acc.y * scale + w * a0.y;
            acc.z = acc.z * scale + w * a0.z;
            acc.w = acc.w * scale + w * a0.w;
            m = mn; v0 = v1; b0 = b1;
        }
        inv = 1.f / s;
    }
    if (l == 0) msum[hs] = make_float2(m, inv);
    acc.x *= inv; acc.y *= inv; acc.z *= inv; acc.w *= inv;
    ((float4*)(aggU + (size_t)h * DIM))[l] = acc;
}

// ---- Epilogue ----
__global__ __launch_bounds__(256) void wout(
    const int* __restrict__ head, const int* __restrict__ uidx,
    const float* __restrict__ e_sc, const float* __restrict__ patt,
    const unsigned int* __restrict__ slotu, const float2* __restrict__ msum,
    float* __restrict__ w1, float* __restrict__ attw, int E, int I, int nE) {
    int t = blockIdx.x * blockDim.x + threadIdx.x;
    if (t < E) {
        float2 mi = msum[head[t]];
        w1[t] = __expf(e_sc[t] - mi.x) * mi.y;
    } else if (t < E + I) {
        int e = t - E;
        float2 mi = msum[nE + uidx[e]];
        attw[e] = __expf(patt[slotu[e]] - mi.x) * mi.y;
    }
}

extern "C" void kernel_launch(void* const* d_in, const int* in_sizes, int n_in,
                              void* d_out, int out_size, void* d_ws, size_t ws_size,
                              hipStream_t stream) {
    const float* ent  = (const float*)d_in[0];
    const float* usr  = (const float*)d_in[1];
    const float* itc  = (const float*)d_in[2];
    const float* rel  = (const float*)d_in[3];
    const int* eidx   = (const int*)d_in[4];
    const int* etype  = (const int*)d_in[5];
    const int* uidx   = (const int*)d_in[6];
    const int* iidx   = (const int*)d_in[7];
    const int* ttype  = (const int*)d_in[8];

    const int E  = in_sizes[4] / 2;
    const int I  = in_sizes[6];
    const int nE = in_sizes[0] / DIM;
    const int nU = in_sizes[1] / DIM;
    const int* head = eidx;
    const int* tail = eidx + E;
    const int NSEG = nE + nU;
    const int NB = (NSEG + SCAN_B - 1) / SCAN_B;
    const int Q = (E + I + 3) / 4;

    float* out_entity = (float*)d_out;
    float* out_user   = out_entity + (size_t)nE * DIM;
    float* out_attw   = out_user + (size_t)nU * DIM;
    float* out_w1     = out_attw + I;

    // workspace layout (u32 units)
    unsigned int* degS      = (unsigned int*)d_ws;                 // 4*NSEG
    unsigned int* sortb     = degS + 4 * (size_t)NSEG;             // 128 bins (zeroed w/ degS)
    unsigned int* offs0     = sortb + 128;                         // NSEG+2
    unsigned int* offs123   = offs0 + NSEG + 2;                    // 3*NSEG
    unsigned int* part      = offs123 + 3 * (size_t)NSEG;          // 1024
    unsigned int* order     = part + 1024;                         // NSEG
    unsigned int* padw      = order + NSEG;                        // pad to even
    unsigned long long* pay64 = (unsigned long long*)(((size_t)(padw - (unsigned int*)d_ws) & 1)
                                ? padw + 1 : padw);                // E u64
    unsigned int* payu      = (unsigned int*)(pay64 + E);          // I
    float* e_sc             = (float*)(payu + I);                  // E
    unsigned int* slotu     = (unsigned int*)(e_sc + E);           // I
    unsigned int* Mreg      = slotu + I;
    __hip_bfloat16* M       = (__hip_bfloat16*)Mreg;               // nE*RELS bf16
    float2* msum            = (float2*)Mreg;                       // aliases M (dead after scatter32)
    float* patt             = (float*)(msum + NSEG);               // I
    uint2* entH             = (uint2*)(Mreg + (size_t)nE * 16);    // nE*16 uint2
    unsigned char* rank_e   = (unsigned char*)(entH + (size_t)nE * 16); // E bytes
    unsigned char* rank_i   = rank_e + E;                          // I bytes

    hipMemsetAsync(degS, 0, (4 * (size_t)NSEG + 128) * sizeof(unsigned int), stream);

    const int T = 256;
    const int gM  = (nE + TILE_V - 1) / TILE_V;
    const int gD  = (E + I + T - 1) / T;
    const int NG  = ((gM + 1) / 2 > (gD + 4) / 5) ? (gM + 1) / 2 : (gD + 4) / 5;
    const int gAE = (int)(((size_t)nE * 16 + T - 1) / T);
    const int gAU = (int)(((size_t)nU * 16 + T - 1) / T);
    const int gSE = (nE + T - 1) / T;
    const int gSU = (nU + T - 1) / T;

    buildM_deg<<<dim3((unsigned)(NG * 7)), T, 0, stream>>>(
        ent, rel, M, entH, head, uidx, degS, rank_e, rank_i, nE, E, I, gM, Q, NSEG);

    scan_partial<<<dim3((unsigned)NB), SCAN_B, 0, stream>>>(degS, part, NSEG);
    scan_block<<<dim3(1), 1024, 0, stream>>>(part, NB);
    scan_final<<<dim3((unsigned)NB), SCAN_B, 0, stream>>>(
        degS, part, offs0, offs123, NSEG, (unsigned)(E + I));

    // degree-sort segment ids (entity range, user range)
    sort_hist<<<dim3((unsigned)gSE), T, 0, stream>>>(offs0, sortb, 0, nE);
    sort_hist<<<dim3((unsigned)gSU), T, 0, stream>>>(offs0, sortb + 64, nE, nU);
    sort_scan<<<dim3(1), 128, 0, stream>>>(sortb, nE);
    sort_scatter<<<dim3((unsigned)gSE), T, 0, stream>>>(offs0, sortb, order, 0, nE, 0);
    sort_scatter<<<dim3((unsigned)gSU), T, 0, stream>>>(offs0, sortb, order, nE, nU, 64);

    scatter32<<<dim3((unsigned)gD), T, 0, stream>>>(
        M, head, tail, etype, uidx, iidx, ttype, rank_e, rank_i, offs0, offs123,
        pay64, payu, e_sc, slotu, E, I, nE, Q, NSEG);

    fused_agg<<<dim3((unsigned)(gAE + gAU)), T, 0, stream>>>(
        entH, usr, itc, pay64, payu, offs0, order, patt, msum,
        out_entity, out_user, nE, nU, E, gAE);

    wout<<<dim3((unsigned)gD), T, 0, stream>>>(
        head, uidx, e_sc, patt, slotu, msum, out_w1, out_attw, E, I, nE);
}

// Round 14
// 292.087 us; speedup vs baseline: 1.1575x; 1.1575x over previous
//
#include <hip/hip_runtime.h>
#include <hip/hip_bf16.h>
#include <hip/hip_fp16.h>

#define DIM 64
#define RELS 32
#define SCAN_B 512
#define TILE_V 64

// ---- fp16 helpers: pack 2 floats -> u32, decode uint2 (4 halves) -> float4 ----
__device__ __forceinline__ unsigned int pk_h2(float a, float b) {
    __half2 h = __float22half2_rn(make_float2(a, b));
    return *reinterpret_cast<unsigned int*>(&h);
}
__device__ __forceinline__ float4 h4_to_f4(uint2 u) {
    __half2 h0 = *reinterpret_cast<__half2*>(&u.x);
    __half2 h1 = *reinterpret_cast<__half2*>(&u.y);
    float2 f0 = __half22float2(h0);
    float2 f1 = __half22float2(h1);
    return make_float4(f0.x, f0.y, f1.x, f1.y);
}

// ============ Kernel A: build_M + fp16 mirror, INTERLEAVED with degree/rank ============
// bid%7: slots 0-1 = build blocks, slots 2-6 = degree blocks -> both types co-resident,
// so the VALU/LDS build phase hides under the atomic-latency degree phase.
__global__ __launch_bounds__(256, 4) void buildM_deg(
    const float* __restrict__ ent, const float* __restrict__ rel,
    __hip_bfloat16* __restrict__ M, uint2* __restrict__ entH,
    const int* __restrict__ head, const int* __restrict__ uidx,
    unsigned int* __restrict__ deg,
    unsigned char* __restrict__ rank_e, unsigned char* __restrict__ rank_i,
    int nE, int E, int I, int gM) {
    __shared__ float4 entL[TILE_V * 17];
    __shared__ float relS[4][16][33];
    int tx = threadIdx.x;
    int bid = blockIdx.x;
    int g = bid / 7, slot = bid - g * 7;

    if (slot >= 2) {
        // ---- degree/rank blocks: plain u32 counters ----
        int t = (g * 5 + (slot - 2)) * 256 + tx;
        if (t < E) {
            rank_e[t] = (unsigned char)atomicAdd(&deg[head[t]], 1u);
        } else if (t < E + I) {
            int e = t - E;
            rank_i[e] = (unsigned char)atomicAdd(&deg[nE + uidx[e]], 1u);
        }
        return;
    }

    // ---- build blocks ----
    int mb = g * 2 + slot;
    if (mb >= gM) return;
    int vg = tx >> 4, rg = tx & 15;
    int base = mb * TILE_V;
    const float4* rel4 = (const float4*)rel;
    #pragma unroll
    for (int k = 0; k < 2; k++) {
        int idx = tx + k * 256;
        float4 v = rel4[idx];
        int r = idx >> 4, d4 = idx & 15;
        relS[0][d4][r] = v.x; relS[1][d4][r] = v.y;
        relS[2][d4][r] = v.z; relS[3][d4][r] = v.w;
    }
    const float4* ent4 = (const float4*)ent;
    #pragma unroll
    for (int k = 0; k < 4; k++) {
        int idx = tx + k * 256;
        int row = idx >> 4, col = idx & 15;
        int v = base + row;
        float4 val = make_float4(0.f, 0.f, 0.f, 0.f);
        if (v < nE) {
            val = ent4[(size_t)v * 16 + col];
            entH[(size_t)v * 16 + col] = make_uint2(pk_h2(val.x, val.y), pk_h2(val.z, val.w));
        }
        entL[row * 17 + col] = val;
    }
    __syncthreads();

    float acc[4][2] = {{0.f,0.f},{0.f,0.f},{0.f,0.f},{0.f,0.f}};
    int r0 = rg * 2;
    #pragma unroll 2
    for (int d4 = 0; d4 < 16; d4++) {
        float4 a0 = entL[(vg * 4 + 0) * 17 + d4];
        float4 a1 = entL[(vg * 4 + 1) * 17 + d4];
        float4 a2 = entL[(vg * 4 + 2) * 17 + d4];
        float4 a3 = entL[(vg * 4 + 3) * 17 + d4];
        float bx0 = relS[0][d4][r0],     by0 = relS[1][d4][r0];
        float bz0 = relS[2][d4][r0],     bw0 = relS[3][d4][r0];
        float bx1 = relS[0][d4][r0 + 1], by1 = relS[1][d4][r0 + 1];
        float bz1 = relS[2][d4][r0 + 1], bw1 = relS[3][d4][r0 + 1];
        acc[0][0] = fmaf(a0.x,bx0, fmaf(a0.y,by0, fmaf(a0.z,bz0, fmaf(a0.w,bw0, acc[0][0]))));
        acc[1][0] = fmaf(a1.x,bx0, fmaf(a1.y,by0, fmaf(a1.z,bz0, fmaf(a1.w,bw0, acc[1][0]))));
        acc[2][0] = fmaf(a2.x,bx0, fmaf(a2.y,by0, fmaf(a2.z,bz0, fmaf(a2.w,bw0, acc[2][0]))));
        acc[3][0] = fmaf(a3.x,bx0, fmaf(a3.y,by0, fmaf(a3.z,bz0, fmaf(a3.w,bw0, acc[3][0]))));
        acc[0][1] = fmaf(a0.x,bx1, fmaf(a0.y,by1, fmaf(a0.z,bz1, fmaf(a0.w,bw1, acc[0][1]))));
        acc[1][1] = fmaf(a1.x,bx1, fmaf(a1.y,by1, fmaf(a1.z,bz1, fmaf(a1.w,bw1, acc[1][1]))));
        acc[2][1] = fmaf(a2.x,bx1, fmaf(a2.y,by1, fmaf(a2.z,bz1, fmaf(a2.w,bw1, acc[2][1]))));
        acc[3][1] = fmaf(a3.x,bx1, fmaf(a3.y,by1, fmaf(a3.z,bz1, fmaf(a3.w,bw1, acc[3][1]))));
    }
    __hip_bfloat162* M2 = (__hip_bfloat162*)M;
    #pragma unroll
    for (int i = 0; i < 4; i++) {
        int v = base + vg * 4 + i;
        if (v < nE) {
            __hip_bfloat16 h0 = __float2bfloat16(acc[i][0] * 0.125f);
            __hip_bfloat16 h1 = __float2bfloat16(acc[i][1] * 0.125f);
            M2[(size_t)v * 16 + rg] = __halves2bfloat162(h0, h1);
        }
    }
}

// ---- Scan step 1: per-block reduce of u32 degrees ----
__global__ __launch_bounds__(SCAN_B) void scan_partial(
    const unsigned int* __restrict__ deg, unsigned int* __restrict__ part, int n) {
    __shared__ unsigned int lds[SCAN_B];
    int i = blockIdx.x * SCAN_B + threadIdx.x;
    lds[threadIdx.x] = (i < n) ? deg[i] : 0u;
    __syncthreads();
    for (int off = SCAN_B >> 1; off > 0; off >>= 1) {
        if (threadIdx.x < off) lds[threadIdx.x] += lds[threadIdx.x + off];
        __syncthreads();
    }
    if (threadIdx.x == 0) part[blockIdx.x] = lds[0];
}

// ---- Scan step 2: single-block exclusive scan of partials ----
__global__ __launch_bounds__(1024) void scan_block(unsigned int* __restrict__ part, int nb) {
    __shared__ unsigned int lds[1024];
    int t = threadIdx.x;
    unsigned int v = (t < nb) ? part[t] : 0u;
    lds[t] = v;
    __syncthreads();
    for (int off = 1; off < 1024; off <<= 1) {
        unsigned int x = (t >= off) ? lds[t - off] : 0u;
        __syncthreads();
        lds[t] += x;
        __syncthreads();
    }
    if (t < nb) part[t] = lds[t] - v;
}

// ---- Scan step 3: in-block exclusive scan + block offset -> offs ----
__global__ __launch_bounds__(SCAN_B) void scan_final(
    const unsigned int* __restrict__ deg, const unsigned int* __restrict__ part,
    unsigned int* __restrict__ offs, int n) {
    __shared__ unsigned int lds[SCAN_B];
    int t = threadIdx.x;
    int i = blockIdx.x * SCAN_B + t;
    unsigned int v = (i < n) ? deg[i] : 0u;
    lds[t] = v;
    __syncthreads();
    for (int off = 1; off < SCAN_B; off <<= 1) {
        unsigned int x = (t >= off) ? lds[t - off] : 0u;
        __syncthreads();
        lds[t] += x;
        __syncthreads();
    }
    if (i < n) offs[i] = part[blockIdx.x] + lds[t] - v;
}

// ---- Scatter: single random-M pass; pay64={score,tail}; e_sc in edge order ----
__global__ __launch_bounds__(256) void scatter32(
    const __hip_bfloat16* __restrict__ M,
    const int* __restrict__ head, const int* __restrict__ tail, const int* __restrict__ etype,
    const int* __restrict__ uidx, const int* __restrict__ iidx, const int* __restrict__ ttype,
    const unsigned char* __restrict__ rank_e, const unsigned char* __restrict__ rank_i,
    const unsigned int* __restrict__ offs,
    unsigned long long* __restrict__ pay64, unsigned int* __restrict__ payu,
    float* __restrict__ e_sc, int E, int I, int nE) {
    int t = blockIdx.x * blockDim.x + threadIdx.x;
    if (t < E) {
        int tl = tail[t];
        float sc = __bfloat162float(M[(size_t)tl * RELS + (etype[t] - 1)]);
        e_sc[t] = sc;
        unsigned int p = offs[head[t]] + rank_e[t];
        unsigned long long v = ((unsigned long long)__float_as_uint(sc) << 32) | (unsigned int)tl;
        __builtin_nontemporal_store(v, &pay64[p]);
    } else if (t < E + I) {
        int e = t - E;
        unsigned int p = offs[nE + uidx[e]] + rank_i[e] - (unsigned)E;
        unsigned int v = (unsigned int)iidx[e] | ((unsigned int)ttype[e] << 27);
        __builtin_nontemporal_store(v, &payu[p]);
    }
}

// ============ Kernel C: entity-agg + user-fused, both on fp16 rows ============
__global__ __launch_bounds__(256) void fused_agg(
    const uint2* __restrict__ entH, const float* __restrict__ usr,
    const float* __restrict__ itc,
    const unsigned long long* __restrict__ pay64, const unsigned int* __restrict__ payu,
    const unsigned int* __restrict__ deg, const unsigned int* __restrict__ offs,
    float* __restrict__ patt, float2* __restrict__ msum,
    float* __restrict__ aggE, float* __restrict__ aggU,
    int nE, int nU, int E, int gAE) {
    __shared__ float4 itcL[8][16];
    int tx = threadIdx.x;
    int bid = blockIdx.x;

    if (bid < gAE) {
        // ---- entity segments: sequential pay64 scores, fp16 row gather (2 lines/row) ----
        int t = bid * 256 + tx;
        int h = t >> 4, l = t & 15;
        if (h >= nE) return;
        unsigned int d = deg[h];
        float m = -3.0e38f, s = 0.f, inv = 0.f;
        float4 acc = make_float4(0.f, 0.f, 0.f, 0.f);
        if (d) {
            unsigned int off = offs[h];
            unsigned long long v0 = pay64[off];
            uint2 b0 = entH[(size_t)(unsigned int)(v0 & 0xffffffffu) * 16 + l];
            for (unsigned int j = 0; j < d; j++) {
                unsigned long long v1 = v0; uint2 b1 = b0;
                if (j + 1 < d) {
                    v1 = pay64[off + j + 1];
                    b1 = entH[(size_t)(unsigned int)(v1 & 0xffffffffu) * 16 + l];
                }
                float sc = __uint_as_float((unsigned int)(v0 >> 32));
                float4 a0 = h4_to_f4(b0);
                float mn = fmaxf(m, sc);
                float scale = __expf(m - mn);
                float w = __expf(sc - mn);
                s = s * scale + w;
                acc.x = acc.x * scale + w * a0.x;
                acc.y = acc.y * scale + w * a0.y;
                acc.z = acc.z * scale + w * a0.z;
                acc.w = acc.w * scale + w * a0.w;
                m = mn; v0 = v1; b0 = b1;
            }
            inv = 1.f / s;
        }
        if (l == 0) msum[h] = make_float2(m, inv);
        acc.x *= inv; acc.y *= inv; acc.z *= inv; acc.w *= inv;
        ((float4*)(aggE + (size_t)h * DIM))[l] = acc;
        return;
    }

    // ---- user segments: fp16 rows (11-bit mantissa: score err ~0.002, safe) ----
    if (tx < 128) itcL[tx >> 4][tx & 15] = ((const float4*)itc)[tx];
    __syncthreads();
    int t = (bid - gAE) * 256 + tx;
    int h = t >> 4, l = t & 15;
    if (h >= nU) return;
    int hs = nE + h;
    unsigned int d = deg[hs];
    float m = -3.0e38f, s = 0.f, inv = 0.f;
    float4 acc = make_float4(0.f, 0.f, 0.f, 0.f);
    float4 ur = ((const float4*)(usr + (size_t)h * DIM))[l];
    if (d) {
        unsigned int off = offs[hs] - (unsigned)E;
        unsigned int v0 = payu[off];
        uint2 b0 = entH[(size_t)(v0 & 0x7ffffffu) * 16 + l];
        for (unsigned int j = 0; j < d; j++) {
            unsigned int v1 = v0; uint2 b1 = b0;
            if (j + 1 < d) {
                v1 = payu[off + j + 1];
                b1 = entH[(size_t)(v1 & 0x7ffffffu) * 16 + l];
            }
            float4 a0 = h4_to_f4(b0);
            float4 c = itcL[v0 >> 27][l];
            float p = a0.x * ur.x * c.x + a0.y * ur.y * c.y
                    + a0.z * ur.z * c.z + a0.w * ur.w * c.w;
            p += __shfl_xor(p, 1);
            p += __shfl_xor(p, 2);
            p += __shfl_xor(p, 4);
            p += __shfl_xor(p, 8);
            if (l == 0) patt[off + j] = p;
            float mn = fmaxf(m, p);
            float scale = __expf(m - mn);
            float w = __expf(p - mn);
            s = s * scale + w;
            acc.x = acc.x * scale + w * a0.x;
            acc.y = acc.y * scale + w * a0.y;
            acc.z = acc.z * scale + w * a0.z;
            acc.w = acc.w * scale + w * a0.w;
            m = mn; v0 = v1; b0 = b1;
        }
        inv = 1.f / s;
    }
    if (l == 0) msum[hs] = make_float2(m, inv);
    acc.x *= inv; acc.y *= inv; acc.z *= inv; acc.w *= inv;
    ((float4*)(aggU + (size_t)h * DIM))[l] = acc;
}

// ---- Epilogue: coalesced per-edge weight writes (sequential score reads) ----
__global__ __launch_bounds__(256) void wout(
    const int* __restrict__ head, const int* __restrict__ uidx,
    const float* __restrict__ e_sc, const float* __restrict__ patt,
    const unsigned char* __restrict__ rank_i,
    const unsigned int* __restrict__ offs, const float2* __restrict__ msum,
    float* __restrict__ w1, float* __restrict__ attw, int E, int I, int nE) {
    int t = blockIdx.x * blockDim.x + threadIdx.x;
    if (t < E) {
        float2 mi = msum[head[t]];
        w1[t] = __expf(e_sc[t] - mi.x) * mi.y;
    } else if (t < E + I) {
        int e = t - E; int u = uidx[e];
        float2 mi = msum[nE + u];
        float sc = patt[offs[nE + u] - (unsigned)E + rank_i[e]];
        attw[e] = __expf(sc - mi.x) * mi.y;
    }
}

extern "C" void kernel_launch(void* const* d_in, const int* in_sizes, int n_in,
                              void* d_out, int out_size, void* d_ws, size_t ws_size,
                              hipStream_t stream) {
    const float* ent  = (const float*)d_in[0];
    const float* usr  = (const float*)d_in[1];
    const float* itc  = (const float*)d_in[2];
    const float* rel  = (const float*)d_in[3];
    const int* eidx   = (const int*)d_in[4];
    const int* etype  = (const int*)d_in[5];
    const int* uidx   = (const int*)d_in[6];
    const int* iidx   = (const int*)d_in[7];
    const int* ttype  = (const int*)d_in[8];

    const int E  = in_sizes[4] / 2;
    const int I  = in_sizes[6];
    const int nE = in_sizes[0] / DIM;
    const int nU = in_sizes[1] / DIM;
    const int* head = eidx;
    const int* tail = eidx + E;
    const int NSEG = nE + nU;
    const int NB = (NSEG + SCAN_B - 1) / SCAN_B;   // <= 1024

    float* out_entity = (float*)d_out;
    float* out_user   = out_entity + (size_t)nE * DIM;
    float* out_attw   = out_user + (size_t)nU * DIM;
    float* out_w1     = out_attw + I;

    // workspace layout (u32 units; alignment by construction)
    unsigned int* deg       = (unsigned int*)d_ws;                 // NSEG
    unsigned int* offs      = deg + NSEG;                          // NSEG
    unsigned int* part      = offs + NSEG;                         // 1024
    unsigned long long* pay64 = (unsigned long long*)(part + 1024); // E u64
    unsigned int* payu      = (unsigned int*)(pay64 + E);          // I
    float* e_sc             = (float*)(payu + I);                  // E
    __hip_bfloat16* M       = (__hip_bfloat16*)(e_sc + E);         // nE*RELS bf16
    uint2* entH             = (uint2*)(M + (size_t)nE * RELS);     // nE*16 uint2 (fp16)
    float2* msum            = (float2*)(entH + (size_t)nE * 16);   // NSEG
    float* patt             = (float*)(msum + NSEG);               // I
    unsigned char* rank_e   = (unsigned char*)(patt + I);          // E bytes
    unsigned char* rank_i   = rank_e + E;                          // I bytes

    hipMemsetAsync(deg, 0, (size_t)NSEG * sizeof(unsigned int), stream);

    const int T = 256;
    const int gM  = (nE + TILE_V - 1) / TILE_V;                    // 3125
    const int gD  = (E + I + T - 1) / T;                           // 7813
    const int NG  = ((gM + 1) / 2 > (gD + 4) / 5) ? (gM + 1) / 2 : (gD + 4) / 5;
    const int gAE = (int)(((size_t)nE * 16 + T - 1) / T);
    const int gAU = (int)(((size_t)nU * 16 + T - 1) / T);

    // A: interleaved build(2/7) + degree(5/7) blocks
    buildM_deg<<<dim3((unsigned)(NG * 7)), T, 0, stream>>>(
        ent, rel, M, entH, head, uidx, deg, rank_e, rank_i, nE, E, I, gM);

    // scans over u32 degrees -> CSR offsets
    scan_partial<<<dim3((unsigned)NB), SCAN_B, 0, stream>>>(deg, part, NSEG);
    scan_block<<<dim3(1), 1024, 0, stream>>>(part, NB);
    scan_final<<<dim3((unsigned)NB), SCAN_B, 0, stream>>>(deg, part, offs, NSEG);

    scatter32<<<dim3((unsigned)gD), T, 0, stream>>>(
        M, head, tail, etype, uidx, iidx, ttype, rank_e, rank_i, offs,
        pay64, payu, e_sc, E, I, nE);

    fused_agg<<<dim3((unsigned)(gAE + gAU)), T, 0, stream>>>(
        entH, usr, itc, pay64, payu, deg, offs, patt, msum,
        out_entity, out_user, nE, nU, E, gAE);

    wout<<<dim3((unsigned)gD), T, 0, stream>>>(
        head, uidx, e_sc, patt, rank_i, offs, msum, out_w1, out_attw, E, I, nE);
}